// Round 5
// baseline (1082.790 us; speedup 1.0000x reference)
//
#include <hip/hip_runtime.h>
#include <hip/hip_fp16.h>

#define BATCH   64
#define NCAPS   32
#define NROUTES 2048
#define INDIM   16
#define OUTDIM  32

typedef _Float16 f16;
typedef __attribute__((ext_vector_type(2)))  _Float16 f16x2;
typedef __attribute__((ext_vector_type(4)))  _Float16 f16x4;
typedef __attribute__((ext_vector_type(8)))  _Float16 f16x8;
typedef __attribute__((ext_vector_type(16))) float    f32x16;

#if defined(__has_builtin)
#if __has_builtin(__builtin_amdgcn_fdot2)
#define HAVE_FDOT2 1
#endif
#endif

// ============================================================
// Kernel 0: split x (fp32) into hi/lo fp16 arrays (read once, reused 32x by c).
// ============================================================
__global__ __launch_bounds__(256) void xsplit(
    const float* __restrict__ x, f16* __restrict__ xh, f16* __restrict__ xl)
{
    int i = blockIdx.x * 256 + threadIdx.x;      // 524288 threads, 4 floats each
    float4 v = ((const float4*)x)[i];
    f16 h0 = (f16)v.x, h1 = (f16)v.y, h2 = (f16)v.z, h3 = (f16)v.w;
    f16x4 hh = {h0, h1, h2, h3};
    f16x4 ll = {(f16)(v.x - (float)h0), (f16)(v.y - (float)h1),
                (f16)(v.z - (float)h2), (f16)(v.w - (float)h3)};
    ((f16x4*)xh)[i] = hh;
    ((f16x4*)xl)[i] = ll;
}

// ============================================================
// Kernel A: priors via split-fp16 MFMA (fp32-accurate product).
// Layout: pri[c][nt][b][nn][o], nt=n>>3, nn=n&7 -> each wave's 8-node group
// is a contiguous 32 KB block (fixes the 4-MiB-strided scatter stores).
// Block 256 thr = 4 waves; wave handles one nt (8 nodes); grid 32c x 64.
// MFMA 32x32x16: A[m=lane&31][k=(lane>>5)*8+j], C: col=lane&31,
// row=(r&3)+8*(r>>2)+4*(lane>>5).
// ============================================================
template<bool SPLITX>
__global__ __launch_bounds__(256, 3) void caps_priors(
    const float* __restrict__ x,
    const float* __restrict__ W,
    const f16* __restrict__ xh,
    const f16* __restrict__ xl,
    f16* __restrict__ pri)
{
    const int bid  = blockIdx.x;      // 2048
    const int c    = bid >> 6;
    const int ntg  = bid & 63;
    const int t    = threadIdx.x;
    const int wv   = t >> 6;
    const int l    = t & 63;
    const int lo31 = l & 31;
    const int h    = l >> 5;
    const int nt   = ntg * 4 + wv;

    f16* const ptile = pri + (size_t)(c * 256 + nt) * 64 * 256 + lo31;

    #pragma unroll 2
    for (int nn = 0; nn < 8; ++nn) {
        const int n = nt * 8 + nn;

        // ---- B fragment: W[c][n][k=h*8+j][o=lo31], contiguous 1KB/half-wave ----
        const float* wb = W + (((size_t)c * NROUTES + n) * INDIM + h * 8) * OUTDIM + lo31;
        f16x8 Bh, Bl;
        #pragma unroll
        for (int j = 0; j < 8; ++j) {
            float v = wb[j * OUTDIM];
            f16 hi = (f16)v;
            Bh[j] = hi;
            Bl[j] = (f16)(v - (float)hi);
        }

        // ---- A fragments: x[b][n][k=h*8+j]; A1: b=lo31, A2: b=lo31+32 ----
        f16x8 A1h, A1l, A2h, A2l;
        if (SPLITX) {
            const f16* ah = xh + ((size_t)lo31 * NROUTES + n) * INDIM + h * 8;
            const f16* al = xl + ((size_t)lo31 * NROUTES + n) * INDIM + h * 8;
            A1h = *(const f16x8*)ah;
            A1l = *(const f16x8*)al;
            A2h = *(const f16x8*)(ah + (size_t)32 * NROUTES * INDIM);
            A2l = *(const f16x8*)(al + (size_t)32 * NROUTES * INDIM);
        } else {
            const float* xa = x + ((size_t)lo31 * NROUTES + n) * INDIM + h * 8;
            const float* xb = xa + (size_t)32 * NROUTES * INDIM;
            float4 a0 = *(const float4*)xa;
            float4 a1 = *(const float4*)(xa + 4);
            float4 b0 = *(const float4*)xb;
            float4 b1 = *(const float4*)(xb + 4);
            float af[8] = {a0.x,a0.y,a0.z,a0.w,a1.x,a1.y,a1.z,a1.w};
            float bf[8] = {b0.x,b0.y,b0.z,b0.w,b1.x,b1.y,b1.z,b1.w};
            #pragma unroll
            for (int j = 0; j < 8; ++j) {
                f16 h1 = (f16)af[j];
                A1h[j] = h1; A1l[j] = (f16)(af[j] - (float)h1);
                f16 h2 = (f16)bf[j];
                A2h[j] = h2; A2l[j] = (f16)(bf[j] - (float)h2);
            }
        }

        f32x16 acc1 = {};
        acc1 = __builtin_amdgcn_mfma_f32_32x32x16_f16(A1h, Bh, acc1, 0, 0, 0);
        acc1 = __builtin_amdgcn_mfma_f32_32x32x16_f16(A1l, Bh, acc1, 0, 0, 0);
        acc1 = __builtin_amdgcn_mfma_f32_32x32x16_f16(A1h, Bl, acc1, 0, 0, 0);
        f32x16 acc2 = {};
        acc2 = __builtin_amdgcn_mfma_f32_32x32x16_f16(A2h, Bh, acc2, 0, 0, 0);
        acc2 = __builtin_amdgcn_mfma_f32_32x32x16_f16(A2l, Bh, acc2, 0, 0, 0);
        acc2 = __builtin_amdgcn_mfma_f32_32x32x16_f16(A2h, Bl, acc2, 0, 0, 0);

        // ---- store into the wave's contiguous 32KB tile ----
        f16* pb = ptile + nn * 32;
        #pragma unroll
        for (int r = 0; r < 16; ++r) {
            int brow = (r & 3) + 8 * (r >> 2) + 4 * h;
            pb[(size_t)brow * 256]        = (f16)acc1[r];
            pb[(size_t)(brow + 32) * 256] = (f16)acc2[r];
        }
    }
}

// ============================================================
// Kernel B: routing. Block 256 thr = 4 waves per (b,c); lane owns 8 whole
// nodes (contiguous 512 B in the new layout -> immediate-offset dwordx4
// loads, each chunk read exactly once). Agreement via v_dot2_f32_f16.
// ============================================================
__global__ __launch_bounds__(256, 2) void caps_route(
    const f16* __restrict__ pri,
    float* __restrict__ out)
{
    const int bid = blockIdx.x;    // b*32 + c
    const int b = bid >> 5;
    const int c = bid & 31;
    const int t = threadIdx.x;
    const int w = t >> 6;
    const int l = t & 63;
    const int nt = w * 64 + l;

    __shared__ float wmax[4];
    __shared__ float wsum[4];
    __shared__ float swave[4][32];
    __shared__ float outArr[32];

    const uint4* pp = (const uint4*)(pri + ((size_t)(c * 256 + nt) * 64 + b) * 256);
    uint4 q[32];
    #pragma unroll
    for (int k = 0; k < 32; ++k) q[k] = pp[k];
    // q[nn*4+j]: node nn, o = j*8..j*8+7 (8 halves per uint4)

    float Bn[8] = {0.f,0.f,0.f,0.f,0.f,0.f,0.f,0.f};

    for (int it = 0; it < 3; ++it) {
        // per-wave softmax pieces (global rescale at combine)
        float m = Bn[0];
        #pragma unroll
        for (int nn = 1; nn < 8; ++nn) m = fmaxf(m, Bn[nn]);
        #pragma unroll
        for (int mk = 1; mk < 64; mk <<= 1) m = fmaxf(m, __shfl_xor(m, mk, 64));
        float e[8], sm = 0.f;
        #pragma unroll
        for (int nn = 0; nn < 8; ++nn) { e[nn] = __expf(Bn[nn] - m); sm += e[nn]; }
        #pragma unroll
        for (int mk = 1; mk < 64; mk <<= 1) sm += __shfl_xor(sm, mk, 64);
        if (l == 0) { wmax[w] = m; wsum[w] = sm; }

        // s[o] = sum over this lane's 8 nodes of e_n * p[n,o]
        float s[32];
        #pragma unroll
        for (int o = 0; o < 32; ++o) s[o] = 0.f;
        #pragma unroll
        for (int nn = 0; nn < 8; ++nn) {
            const f16x2* ph = (const f16x2*)&q[nn * 4];
            float en = e[nn];
            #pragma unroll
            for (int p = 0; p < 16; ++p) {
                s[2*p]   += en * (float)ph[p][0];
                s[2*p+1] += en * (float)ph[p][1];
            }
        }

        // log-split transpose-reduce across 64 lanes (verified in round 3)
        #pragma unroll
        for (int step = 0; step < 5; ++step) {
            const int mk = 1 << step;
            const int half = 16 >> step;
            bool bit = (l & mk) != 0;
            #pragma unroll
            for (int k = 0; k < half; ++k) {
                float keep = bit ? s[k + half] : s[k];
                float send = bit ? s[k] : s[k + half];
                s[k] = keep + __shfl_xor(send, mk, 64);
            }
        }
        s[0] += __shfl_xor(s[0], 32, 64);
        int orev = __brev(l & 31) >> 27;
        if (l < 32) swave[w][orev] = s[0];
        __syncthreads();

        if (t < 32) {
            float M = fmaxf(fmaxf(wmax[0], wmax[1]), fmaxf(wmax[2], wmax[3]));
            float S = 0.f, sv = 0.f;
            #pragma unroll
            for (int k = 0; k < 4; ++k) {
                float sc = __expf(wmax[k] - M);
                S  += wsum[k] * sc;
                sv += swave[k][t] * sc;
            }
            sv /= S;
            float sq = sv * sv;
            sq += __shfl_xor(sq, 1, 64);
            sq += __shfl_xor(sq, 2, 64);
            sq += __shfl_xor(sq, 4, 64);
            sq += __shfl_xor(sq, 8, 64);
            sq += __shfl_xor(sq, 16, 64);
            float scale = sq / ((1.f + sq) * sqrtf(sq));
            float ov = sv * scale;
            if (it == 2) out[((size_t)b * NCAPS + c) * OUTDIM + t] = ov;
            else         outArr[t] = ov;
        }

        if (it < 2) {
            __syncthreads();
            f16x2 oh[16];
            #pragma unroll
            for (int k = 0; k < 8; ++k) {
                float4 v = ((const float4*)outArr)[k];
                oh[2*k]   = f16x2{(f16)v.x, (f16)v.y};
                oh[2*k+1] = f16x2{(f16)v.z, (f16)v.w};
            }
            #pragma unroll
            for (int nn = 0; nn < 8; ++nn) {
                const f16x2* ph = (const f16x2*)&q[nn * 4];
                float d = 0.f;
#ifdef HAVE_FDOT2
                #pragma unroll
                for (int p = 0; p < 16; ++p)
                    d = __builtin_amdgcn_fdot2(ph[p], oh[p], d, false);
#else
                #pragma unroll
                for (int p = 0; p < 16; ++p)
                    d += (float)ph[p][0] * (float)oh[p][0]
                       + (float)ph[p][1] * (float)oh[p][1];
#endif
                Bn[nn] += d;
            }
        }
    }
}

// ============================================================
// Fallback (round-1 fused kernel, fp32) if ws is too small.
// ============================================================
__global__ __launch_bounds__(1024, 4) void caps_fused(
    const float* __restrict__ x,
    const float* __restrict__ W,
    float* __restrict__ out)
{
    int blk  = blockIdx.x;
    int xcd  = blk & 7;
    int rest = blk >> 3;
    int c = xcd * 4 + (rest >> 6);
    int b = rest & 63;

    int t   = threadIdx.x;
    int w   = t >> 6;
    int l   = t & 63;
    int o   = l & 31;
    int sub = l >> 5;

    __shared__ float Bsh[NROUTES];
    __shared__ float Psh[NROUTES];
    __shared__ float red[1024];
    __shared__ float spart[16][32];
    __shared__ float outArr[32];

    Bsh[t] = 0.0f;
    Bsh[t + 1024] = 0.0f;

    float p[64];
    const int nodeBase = w * 128 + sub;
    const float* Wc = W + (size_t)c * NROUTES * (INDIM * OUTDIM);
    const float* xb = x + (size_t)b * NROUTES * INDIM;

    #pragma unroll 2
    for (int j = 0; j < 64; ++j) {
        int n = nodeBase + 2 * j;
        const float*  wp = Wc + (size_t)n * (INDIM * OUTDIM) + o;
        const float4* xp = (const float4*)(xb + n * INDIM);
        float4 x0 = xp[0], x1 = xp[1], x2 = xp[2], x3 = xp[3];
        float acc = 0.0f;
        acc += x0.x * wp[ 0*32]; acc += x0.y * wp[ 1*32];
        acc += x0.z * wp[ 2*32]; acc += x0.w * wp[ 3*32];
        acc += x1.x * wp[ 4*32]; acc += x1.y * wp[ 5*32];
        acc += x1.z * wp[ 6*32]; acc += x1.w * wp[ 7*32];
        acc += x2.x * wp[ 8*32]; acc += x2.y * wp[ 9*32];
        acc += x2.z * wp[10*32]; acc += x2.w * wp[11*32];
        acc += x3.x * wp[12*32]; acc += x3.y * wp[13*32];
        acc += x3.z * wp[14*32]; acc += x3.w * wp[15*32];
        p[j] = acc;
    }
    __syncthreads();

    for (int it = 0; it < 3; ++it) {
        float m = fmaxf(Bsh[t], Bsh[t + 1024]);
        red[t] = m;
        __syncthreads();
        for (int s = 512; s >= 1; s >>= 1) {
            if (t < s) red[t] = fmaxf(red[t], red[t + s]);
            __syncthreads();
        }
        float M = red[0];
        __syncthreads();

        float e0 = __expf(Bsh[t] - M);
        float e1 = __expf(Bsh[t + 1024] - M);
        Psh[t] = e0;
        Psh[t + 1024] = e1;
        red[t] = e0 + e1;
        __syncthreads();
        for (int s = 512; s >= 1; s >>= 1) {
            if (t < s) red[t] += red[t + s];
            __syncthreads();
        }
        float invS = 1.0f / red[0];
        __syncthreads();

        float local = 0.0f;
        #pragma unroll 8
        for (int j = 0; j < 64; ++j) local += Psh[nodeBase + 2 * j] * p[j];
        local *= invS;
        local += __shfl_xor(local, 32, 64);
        if (l < 32) spart[w][l] = local;
        __syncthreads();

        if (t < 32) {
            float s = 0.0f;
            #pragma unroll
            for (int ww = 0; ww < 16; ++ww) s += spart[ww][t];
            float sq = s * s;
            sq += __shfl_xor(sq, 1, 64);
            sq += __shfl_xor(sq, 2, 64);
            sq += __shfl_xor(sq, 4, 64);
            sq += __shfl_xor(sq, 8, 64);
            sq += __shfl_xor(sq, 16, 64);
            float scale = sq / ((1.0f + sq) * sqrtf(sq));
            outArr[t] = s * scale;
        }
        __syncthreads();

        float outReg = outArr[o];
        if (it < 2) {
            #pragma unroll 8
            for (int j = 0; j < 64; ++j) {
                float a = p[j] * outReg;
                a += __shfl_xor(a, 1, 64);
                a += __shfl_xor(a, 2, 64);
                a += __shfl_xor(a, 4, 64);
                a += __shfl_xor(a, 8, 64);
                a += __shfl_xor(a, 16, 64);
                if ((l & 31) == 0) Bsh[nodeBase + 2 * j] += a;
            }
            __syncthreads();
        }
    }

    if (t < 32) out[((size_t)b * NCAPS + c) * OUTDIM + t] = outArr[t];
}

extern "C" void kernel_launch(void* const* d_in, const int* in_sizes, int n_in,
                              void* d_out, int out_size, void* d_ws, size_t ws_size,
                              hipStream_t stream) {
    const float* x = (const float*)d_in[0];
    const float* W = (const float*)d_in[1];
    float* out = (float*)d_out;

    const size_t priBytes = (size_t)BATCH * NCAPS * NROUTES * OUTDIM * 2;   // 256 MiB
    const size_t xBytes   = (size_t)BATCH * NROUTES * INDIM * 2;            // 4 MiB each
    f16* pri = (f16*)d_ws;
    f16* xh  = (f16*)((char*)d_ws + priBytes);
    f16* xl  = (f16*)((char*)d_ws + priBytes + xBytes);

    if (ws_size >= priBytes + 2 * xBytes) {
        xsplit<<<dim3(2048), dim3(256), 0, stream>>>(x, xh, xl);
        caps_priors<true><<<dim3(2048), dim3(256), 0, stream>>>(x, W, xh, xl, pri);
        caps_route<<<dim3(BATCH * NCAPS), dim3(256), 0, stream>>>(pri, out);
    } else if (ws_size >= priBytes) {
        caps_priors<false><<<dim3(2048), dim3(256), 0, stream>>>(x, W, nullptr, nullptr, pri);
        caps_route<<<dim3(BATCH * NCAPS), dim3(256), 0, stream>>>(pri, out);
    } else {
        caps_fused<<<dim3(BATCH * NCAPS), dim3(1024), 0, stream>>>(x, W, out);
    }
}

// Round 6
// 946.660 us; speedup vs baseline: 1.1438x; 1.1438x over previous
//
#include <hip/hip_runtime.h>
#include <hip/hip_fp16.h>

#define BATCH   64
#define NCAPS   32
#define NROUTES 2048
#define INDIM   16
#define OUTDIM  32

typedef _Float16 f16;
typedef __attribute__((ext_vector_type(4)))  _Float16 f16x4;
typedef __attribute__((ext_vector_type(8)))  _Float16 f16x8;
typedef __attribute__((ext_vector_type(16))) float    f32x16;

// ============================================================
// Kernel 0: split x (fp32) into hi/lo fp16 arrays.
// ============================================================
__global__ __launch_bounds__(256) void xsplit(
    const float* __restrict__ x, f16* __restrict__ xh, f16* __restrict__ xl)
{
    int i = blockIdx.x * 256 + threadIdx.x;
    float4 v = ((const float4*)x)[i];
    f16 h0 = (f16)v.x, h1 = (f16)v.y, h2 = (f16)v.z, h3 = (f16)v.w;
    f16x4 hh = {h0, h1, h2, h3};
    f16x4 ll = {(f16)(v.x - (float)h0), (f16)(v.y - (float)h1),
                (f16)(v.z - (float)h2), (f16)(v.w - (float)h3)};
    ((f16x4*)xh)[i] = hh;
    ((f16x4*)xl)[i] = ll;
}

// ============================================================
// Kernel A: priors via split-fp16 MFMA (fp32-accurate), round-5 structure.
// Layout: pri[c][nt][b][nn][o]  (nt=n>>3, nn=n&7) — wave tile contiguous 32KB.
// ============================================================
template<bool SPLITX>
__global__ __launch_bounds__(256, 3) void caps_priors(
    const float* __restrict__ x,
    const float* __restrict__ W,
    const f16* __restrict__ xh,
    const f16* __restrict__ xl,
    f16* __restrict__ pri)
{
    const int bid  = blockIdx.x;      // 2048
    const int c    = bid >> 6;
    const int ntg  = bid & 63;
    const int t    = threadIdx.x;
    const int wv   = t >> 6;
    const int l    = t & 63;
    const int lo31 = l & 31;
    const int h    = l >> 5;
    const int nt   = ntg * 4 + wv;

    f16* const ptile = pri + (size_t)(c * 256 + nt) * 64 * 256 + lo31;

    #pragma unroll 2
    for (int nn = 0; nn < 8; ++nn) {
        const int n = nt * 8 + nn;

        const float* wb = W + (((size_t)c * NROUTES + n) * INDIM + h * 8) * OUTDIM + lo31;
        f16x8 Bh, Bl;
        #pragma unroll
        for (int j = 0; j < 8; ++j) {
            float v = wb[j * OUTDIM];
            f16 hi = (f16)v;
            Bh[j] = hi;
            Bl[j] = (f16)(v - (float)hi);
        }

        f16x8 A1h, A1l, A2h, A2l;
        if (SPLITX) {
            const f16* ah = xh + ((size_t)lo31 * NROUTES + n) * INDIM + h * 8;
            const f16* al = xl + ((size_t)lo31 * NROUTES + n) * INDIM + h * 8;
            A1h = *(const f16x8*)ah;
            A1l = *(const f16x8*)al;
            A2h = *(const f16x8*)(ah + (size_t)32 * NROUTES * INDIM);
            A2l = *(const f16x8*)(al + (size_t)32 * NROUTES * INDIM);
        } else {
            const float* xa = x + ((size_t)lo31 * NROUTES + n) * INDIM + h * 8;
            const float* xb = xa + (size_t)32 * NROUTES * INDIM;
            float4 a0 = *(const float4*)xa;
            float4 a1 = *(const float4*)(xa + 4);
            float4 b0 = *(const float4*)xb;
            float4 b1 = *(const float4*)(xb + 4);
            float af[8] = {a0.x,a0.y,a0.z,a0.w,a1.x,a1.y,a1.z,a1.w};
            float bf[8] = {b0.x,b0.y,b0.z,b0.w,b1.x,b1.y,b1.z,b1.w};
            #pragma unroll
            for (int j = 0; j < 8; ++j) {
                f16 h1 = (f16)af[j];
                A1h[j] = h1; A1l[j] = (f16)(af[j] - (float)h1);
                f16 h2 = (f16)bf[j];
                A2h[j] = h2; A2l[j] = (f16)(bf[j] - (float)h2);
            }
        }

        f32x16 acc1 = {};
        acc1 = __builtin_amdgcn_mfma_f32_32x32x16_f16(A1h, Bh, acc1, 0, 0, 0);
        acc1 = __builtin_amdgcn_mfma_f32_32x32x16_f16(A1l, Bh, acc1, 0, 0, 0);
        acc1 = __builtin_amdgcn_mfma_f32_32x32x16_f16(A1h, Bl, acc1, 0, 0, 0);
        f32x16 acc2 = {};
        acc2 = __builtin_amdgcn_mfma_f32_32x32x16_f16(A2h, Bh, acc2, 0, 0, 0);
        acc2 = __builtin_amdgcn_mfma_f32_32x32x16_f16(A2l, Bh, acc2, 0, 0, 0);
        acc2 = __builtin_amdgcn_mfma_f32_32x32x16_f16(A2h, Bl, acc2, 0, 0, 0);

        f16* pb = ptile + nn * 32;
        #pragma unroll
        for (int r = 0; r < 16; ++r) {
            int brow = (r & 3) + 8 * (r >> 2) + 4 * h;
            pb[(size_t)brow * 256]        = (f16)acc1[r];
            pb[(size_t)(brow + 32) * 256] = (f16)acc2[r];
        }
    }
}

// ============================================================
// Kernel R: one routing iteration's accumulation, pure streaming.
// B_n = p_n . V  (V = cumulative squashed outputs; V=0 on iter 0 -> uniform).
// Thread (b = t>>2, og = t&3) accumulates T[og*8..+7] and Z for its slab,
// then atomicAdds into G[b][c][33] (T[0..31], Z at [32]).
// Grid: c * 64 slab-groups (slab = 4 nt = 32 nodes). ~40 VGPR, no spills.
// ============================================================
__global__ __launch_bounds__(256, 8) void caps_route_acc(
    const f16* __restrict__ pri,
    const float* __restrict__ V,
    float* __restrict__ G)
{
    const int bid = blockIdx.x;   // c*64 + sg
    const int c   = bid >> 6;
    const int sg  = bid & 63;
    const int t   = threadIdx.x;
    const int b   = t >> 2;
    const int og  = t & 3;

    // this thread's 8 V components (fp32, full precision)
    const float* vp = V + (((size_t)b * NCAPS + c) << 5) + og * 8;
    float4 va = *(const float4*)vp;
    float4 vb = *(const float4*)(vp + 4);
    const float v0[8] = {va.x, va.y, va.z, va.w, vb.x, vb.y, vb.z, vb.w};

    float Tacc[8] = {0.f,0.f,0.f,0.f,0.f,0.f,0.f,0.f};
    float z = 0.f;

    #pragma unroll
    for (int ntl = 0; ntl < 4; ++ntl) {
        const int nt = sg * 4 + ntl;
        const uint4* pp = (const uint4*)pri
                        + ((size_t)(c * 256 + nt) * 64 + b) * 32 + og;
        #pragma unroll
        for (int nn = 0; nn < 8; ++nn) {
            uint4 q = pp[nn * 4];
            const __half2* hp = (const __half2*)&q;
            float pf[8];
            #pragma unroll
            for (int k = 0; k < 4; ++k) {
                float2 f = __half22float2(hp[k]);
                pf[2*k]   = f.x;
                pf[2*k+1] = f.y;
            }
            float d = pf[0]*v0[0] + pf[1]*v0[1] + pf[2]*v0[2] + pf[3]*v0[3]
                    + pf[4]*v0[4] + pf[5]*v0[5] + pf[6]*v0[6] + pf[7]*v0[7];
            d += __shfl_xor(d, 1, 64);
            d += __shfl_xor(d, 2, 64);
            float w = __expf(d);
            z += w;
            #pragma unroll
            for (int k = 0; k < 8; ++k) Tacc[k] += w * pf[k];
        }
    }

    float* g = G + ((size_t)b * NCAPS + c) * 33;
    #pragma unroll
    for (int k = 0; k < 8; ++k) atomicAdd(&g[og * 8 + k], Tacc[k]);
    if (og == 0) atomicAdd(&g[32], z);
}

// ============================================================
// Kernel S: squash + V update + G re-zero (+ final output write).
// 64 blocks x 1024 thr; thread = (pair = b*32+c, o).
// ============================================================
__global__ __launch_bounds__(1024) void caps_route_sq(
    float* __restrict__ G,
    float* __restrict__ V,
    float* __restrict__ out,
    int last)
{
    const int t    = threadIdx.x;
    const int pair = blockIdx.x * 32 + (t >> 5);
    const int o    = t & 31;

    float* g = G + (size_t)pair * 33;
    float T = g[o];
    float Z = g[32];
    float sv = T / Z;
    float sq = sv * sv;
    sq += __shfl_xor(sq, 1, 64);
    sq += __shfl_xor(sq, 2, 64);
    sq += __shfl_xor(sq, 4, 64);
    sq += __shfl_xor(sq, 8, 64);
    sq += __shfl_xor(sq, 16, 64);
    float scale = sq / ((1.f + sq) * sqrtf(sq));
    float v = sv * scale;

    if (last) out[(size_t)pair * 32 + o] = v;
    else      V[(size_t)pair * 32 + o] += v;

    g[o] = 0.f;          // same-wave: reads above already done in lockstep
    if (o == 0) g[32] = 0.f;
}

// ============================================================
// Fallback (round-1 fused kernel, fp32) if ws is too small.
// ============================================================
__global__ __launch_bounds__(1024, 4) void caps_fused(
    const float* __restrict__ x,
    const float* __restrict__ W,
    float* __restrict__ out)
{
    int blk  = blockIdx.x;
    int xcd  = blk & 7;
    int rest = blk >> 3;
    int c = xcd * 4 + (rest >> 6);
    int b = rest & 63;

    int t   = threadIdx.x;
    int w   = t >> 6;
    int l   = t & 63;
    int o   = l & 31;
    int sub = l >> 5;

    __shared__ float Bsh[NROUTES];
    __shared__ float Psh[NROUTES];
    __shared__ float red[1024];
    __shared__ float spart[16][32];
    __shared__ float outArr[32];

    Bsh[t] = 0.0f;
    Bsh[t + 1024] = 0.0f;

    float p[64];
    const int nodeBase = w * 128 + sub;
    const float* Wc = W + (size_t)c * NROUTES * (INDIM * OUTDIM);
    const float* xb = x + (size_t)b * NROUTES * INDIM;

    #pragma unroll 2
    for (int j = 0; j < 64; ++j) {
        int n = nodeBase + 2 * j;
        const float*  wp = Wc + (size_t)n * (INDIM * OUTDIM) + o;
        const float4* xp = (const float4*)(xb + n * INDIM);
        float4 x0 = xp[0], x1 = xp[1], x2 = xp[2], x3 = xp[3];
        float acc = 0.0f;
        acc += x0.x * wp[ 0*32]; acc += x0.y * wp[ 1*32];
        acc += x0.z * wp[ 2*32]; acc += x0.w * wp[ 3*32];
        acc += x1.x * wp[ 4*32]; acc += x1.y * wp[ 5*32];
        acc += x1.z * wp[ 6*32]; acc += x1.w * wp[ 7*32];
        acc += x2.x * wp[ 8*32]; acc += x2.y * wp[ 9*32];
        acc += x2.z * wp[10*32]; acc += x2.w * wp[11*32];
        acc += x3.x * wp[12*32]; acc += x3.y * wp[13*32];
        acc += x3.z * wp[14*32]; acc += x3.w * wp[15*32];
        p[j] = acc;
    }
    __syncthreads();

    for (int it = 0; it < 3; ++it) {
        float m = fmaxf(Bsh[t], Bsh[t + 1024]);
        red[t] = m;
        __syncthreads();
        for (int s = 512; s >= 1; s >>= 1) {
            if (t < s) red[t] = fmaxf(red[t], red[t + s]);
            __syncthreads();
        }
        float M = red[0];
        __syncthreads();

        float e0 = __expf(Bsh[t] - M);
        float e1 = __expf(Bsh[t + 1024] - M);
        Psh[t] = e0;
        Psh[t + 1024] = e1;
        red[t] = e0 + e1;
        __syncthreads();
        for (int s = 512; s >= 1; s >>= 1) {
            if (t < s) red[t] += red[t + s];
            __syncthreads();
        }
        float invS = 1.0f / red[0];
        __syncthreads();

        float local = 0.0f;
        #pragma unroll 8
        for (int j = 0; j < 64; ++j) local += Psh[nodeBase + 2 * j] * p[j];
        local *= invS;
        local += __shfl_xor(local, 32, 64);
        if (l < 32) spart[w][l] = local;
        __syncthreads();

        if (t < 32) {
            float s = 0.0f;
            #pragma unroll
            for (int ww = 0; ww < 16; ++ww) s += spart[ww][t];
            float sq = s * s;
            sq += __shfl_xor(sq, 1, 64);
            sq += __shfl_xor(sq, 2, 64);
            sq += __shfl_xor(sq, 4, 64);
            sq += __shfl_xor(sq, 8, 64);
            sq += __shfl_xor(sq, 16, 64);
            float scale = sq / ((1.0f + sq) * sqrtf(sq));
            outArr[t] = s * scale;
        }
        __syncthreads();

        float outReg = outArr[o];
        if (it < 2) {
            #pragma unroll 8
            for (int j = 0; j < 64; ++j) {
                float a = p[j] * outReg;
                a += __shfl_xor(a, 1, 64);
                a += __shfl_xor(a, 2, 64);
                a += __shfl_xor(a, 4, 64);
                a += __shfl_xor(a, 8, 64);
                a += __shfl_xor(a, 16, 64);
                if ((l & 31) == 0) Bsh[nodeBase + 2 * j] += a;
            }
            __syncthreads();
        }
    }

    if (t < 32) out[((size_t)b * NCAPS + c) * OUTDIM + t] = outArr[t];
}

extern "C" void kernel_launch(void* const* d_in, const int* in_sizes, int n_in,
                              void* d_out, int out_size, void* d_ws, size_t ws_size,
                              hipStream_t stream) {
    const float* x = (const float*)d_in[0];
    const float* W = (const float*)d_in[1];
    float* out = (float*)d_out;

    const size_t priBytes = (size_t)BATCH * NCAPS * NROUTES * OUTDIM * 2;  // 256 MiB
    const size_t xBytes   = (size_t)BATCH * NROUTES * INDIM * 2;           // 4 MiB
    const size_t gBytes   = (size_t)BATCH * NCAPS * 33 * 4;                // 264 KiB
    const size_t vBytes   = (size_t)BATCH * NCAPS * 32 * 4;                // 256 KiB

    if (ws_size >= priBytes + 2 * xBytes + gBytes + vBytes) {
        f16*   pri = (f16*)d_ws;
        f16*   xh  = (f16*)((char*)d_ws + priBytes);
        f16*   xl  = (f16*)((char*)d_ws + priBytes + xBytes);
        float* G   = (float*)((char*)d_ws + priBytes + 2 * xBytes);
        float* V   = (float*)((char*)d_ws + priBytes + 2 * xBytes + gBytes);

        hipMemsetAsync(G, 0, gBytes + vBytes, stream);   // zero G and V
        xsplit<<<dim3(2048), dim3(256), 0, stream>>>(x, xh, xl);
        caps_priors<true><<<dim3(2048), dim3(256), 0, stream>>>(x, W, xh, xl, pri);
        for (int it = 0; it < 3; ++it) {
            caps_route_acc<<<dim3(NCAPS * 64), dim3(256), 0, stream>>>(pri, V, G);
            caps_route_sq<<<dim3(64), dim3(1024), 0, stream>>>(G, V, out, it == 2);
        }
    } else if (ws_size >= priBytes + gBytes + vBytes) {
        f16*   pri = (f16*)d_ws;
        float* G   = (float*)((char*)d_ws + priBytes);
        float* V   = (float*)((char*)d_ws + priBytes + gBytes);

        hipMemsetAsync(G, 0, gBytes + vBytes, stream);
        caps_priors<false><<<dim3(2048), dim3(256), 0, stream>>>(x, W, nullptr, nullptr, pri);
        for (int it = 0; it < 3; ++it) {
            caps_route_acc<<<dim3(NCAPS * 64), dim3(256), 0, stream>>>(pri, V, G);
            caps_route_sq<<<dim3(64), dim3(1024), 0, stream>>>(G, V, out, it == 2);
        }
    } else {
        caps_fused<<<dim3(BATCH * NCAPS), dim3(1024), 0, stream>>>(x, W, out);
    }
}